// Round 2
// baseline (141.266 us; speedup 1.0000x reference)
//
#include <hip/hip_runtime.h>

// SparseMCFModel — flow depends only on demands/edge_row/edge_col (GAT/GRU dead).
//   V_1[v] = relu(d[v])/deg[v]
//   V_j[v] = (relu(d[v]) + sum_{e:col=v} V_{j-1}[row_e]) / deg[v],  j=2..10
//   out[e] = V_10[row_e]
//
// r16 = r15 (dataflow chain, 2 barriers) + spin watchdogs (hang -> diagnosable
// numeric failure instead of container death).
//  - W[k][v] = V_{k+2}, k=0..8, each level its own buffer (no WAR), memset 0xFF
//    (NaN bit pattern; published values are finite, never 0xFFFFFFFF).
//  - Level 0 (V2) computed directly from inputs (V1 recomputed per edge,
//    bitwise identical to publishing V1) — saves one dataflow hop.
//  - Levels 1..8: owner thread spin-loads its <=24 sources (pending-only
//    batched re-loads for MLP, s_sleep backoff, bounded retries), folds in
//    slot order (deterministic), publishes. No global barrier in the chain.
//  - gbar only post-build and pre-output; non-owners park at s_barrier.
// Soundness as r6-r14: cross-block mutable data via agent-scope atomic ops
// (coherent point); __syncthreads drains vmcnt before s_barrier so pre-barrier
// stores are globally visible before arrival RMW; pcsc lines are fresh-written
// and never read pre-barrier (cannot be cached stale); 128 blocks co-resident
// (worst-case 1 block/CU on 256 CUs).

#define N_NODES 20000
#define N_EDGES 200000
#define FLOW_ITERS 10
#define NBLK 128
#define NTHR 512
#define NPB 157                            // nodes (owners) per block
#define CAP 24                             // padded in-edge slots per node
#define NQUAD 50000                        // N_EDGES/4 int4 quads
#define QPB 391                            // quads per block (391*128 = 50048)
#define OFL_MAX 4096
#define NP1 (N_NODES + 1)
#define NLVL 9                             // W[k] = V_{k+2}, k=0..8 (V2..V10)
#define NANP 0xFFFFFFFFu
#define SPIN_MAX 65536                     // watchdog: ~1000x any legit wait

__device__ __forceinline__ float ld_coh(const float* p) {
    return __hip_atomic_load(p, __ATOMIC_RELAXED, __HIP_MEMORY_SCOPE_AGENT);
}
__device__ __forceinline__ unsigned ld_coh_u(const unsigned* p) {
    return __hip_atomic_load(p, __ATOMIC_RELAXED, __HIP_MEMORY_SCOPE_AGENT);
}
__device__ __forceinline__ int ld_coh_i(const int* p) {
    return __hip_atomic_load(p, __ATOMIC_RELAXED, __HIP_MEMORY_SCOPE_AGENT);
}
__device__ __forceinline__ void st_coh(float* p, float v) {
    __hip_atomic_store(p, v, __ATOMIC_RELAXED, __HIP_MEMORY_SCOPE_AGENT);
}
__device__ __forceinline__ void st_coh_i(int* p, int v) {
    __hip_atomic_store(p, v, __ATOMIC_RELAXED, __HIP_MEMORY_SCOPE_AGENT);
}

// Distributed-arrival barrier (unchanged from r14), with watchdog.
__device__ __forceinline__ void gbar(int* grp, int ord) {
    __syncthreads();
    if (threadIdx.x == 0) {
        __hip_atomic_fetch_add(&grp[(blockIdx.x & 7) * 32], 1,
                               __ATOMIC_RELAXED, __HIP_MEMORY_SCOPE_AGENT);
        const int target = NBLK * ord;
        for (int t = 0; t < SPIN_MAX; ++t) {
            int s = 0;
            #pragma unroll
            for (int g = 0; g < 8; ++g)
                s += __hip_atomic_load(&grp[g * 32], __ATOMIC_RELAXED,
                                       __HIP_MEMORY_SCOPE_AGENT);
            if (s >= target) break;
            __builtin_amdgcn_s_sleep(1);
        }
    }
    __syncthreads();
}

__global__ __launch_bounds__(NTHR)
void mcf_fused(const float* __restrict__ demands,
               const int* __restrict__ edge_row,   // int4-aligned
               const int* __restrict__ edge_col,
               float* __restrict__ out,
               int* __restrict__ deg,       // [N]        zeroed
               int* __restrict__ fill,      // [N]        zeroed
               float* __restrict__ W,       // [NLVL*NP1] memset 0xFF (NaN tags)
               int* __restrict__ pcsc,      // [N*CAP]    uninit
               int* __restrict__ ofl_cnt,   // [1]        zeroed
               int* __restrict__ ofl_v,     // [OFL_MAX]  uninit
               int* __restrict__ ofl_row,   // [OFL_MAX]  uninit
               int* __restrict__ grp)       // [8*32]     zeroed
{
    const int tx = threadIdx.x, bx = blockIdx.x;
    int bar = 0;

    // ---- Build: int4 edge loads, deg/fill atomics, column-local placement ----
    const int m = bx * QPB + tx;
    const bool bld = (tx < QPB) && (m < NQUAD);
    int4 r4 = {0, 0, 0, 0}, c4 = {0, 0, 0, 0};
    if (bld) {
        r4 = ((const int4*)edge_row)[m];
        c4 = ((const int4*)edge_col)[m];
        int rr[4] = {r4.x, r4.y, r4.z, r4.w};
        int cc[4] = {c4.x, c4.y, c4.z, c4.w};
        #pragma unroll
        for (int i = 0; i < 4; ++i) {
            __hip_atomic_fetch_add(&deg[rr[i]], 1, __ATOMIC_RELAXED, __HIP_MEMORY_SCOPE_AGENT);
            int idx = __hip_atomic_fetch_add(&fill[cc[i]], 1,
                                             __ATOMIC_RELAXED, __HIP_MEMORY_SCOPE_AGENT);
            if (idx < CAP) {
                st_coh_i(&pcsc[cc[i] * CAP + idx], rr[i]);
            } else {
                int o = __hip_atomic_fetch_add(ofl_cnt, 1,
                                               __ATOMIC_RELAXED, __HIP_MEMORY_SCOPE_AGENT);
                if (o < OFL_MAX) { st_coh_i(&ofl_v[o], cc[i]); st_coh_i(&ofl_row[o], rr[i]); }
            }
        }
    }
    gbar(grp, ++bar);

    // ---- Owner chain: one thread per node, dataflow across levels ----
    const int v = bx * NPB + tx;
    const bool own = (tx < NPB) && (v < N_NODES);
    if (own) {
        const int cnt = min(ld_coh_i(&fill[v]), CAP);
        int er[CAP];
        {   // six int4 plain loads; lines fresh this dispatch (st_coh-written,
            // never read pre-barrier) -> cannot be cached stale
            const int4* pb = (const int4*)&pcsc[v * CAP];
            #pragma unroll
            for (int qq = 0; qq < 6; ++qq) {
                int4 a = pb[qq];
                er[qq * 4 + 0] = a.x; er[qq * 4 + 1] = a.y;
                er[qq * 4 + 2] = a.z; er[qq * 4 + 3] = a.w;
            }
        }
        const float dposv = fmaxf(demands[v], 0.0f);
        const int   dv    = ld_coh_i(&deg[v]);
        const float invd  = (dv > 0) ? (1.0f / (float)dv) : 0.0f;
        const int   ocnt  = ld_coh_i(ofl_cnt);            // expected 0

        // -- level 0 (V2): sources' V1 recomputed directly from inputs --
        {
            float fd[CAP]; int gd[CAP];
            #pragma unroll
            for (int s = 0; s < CAP; ++s)
                if (s < cnt) { fd[s] = demands[er[s]]; gd[s] = ld_coh_i(&deg[er[s]]); }
            float acc = dposv;
            #pragma unroll
            for (int s = 0; s < CAP; ++s)
                if (s < cnt) acc += fmaxf(fd[s], 0.0f) * (1.0f / (float)gd[s]);
            if (ocnt > 0) {
                for (int o = 0; o < ocnt && o < OFL_MAX; ++o)
                    if (ld_coh_i(&ofl_v[o]) == v) {
                        int r = ld_coh_i(&ofl_row[o]);
                        acc += fmaxf(demands[r], 0.0f)
                             * (1.0f / (float)ld_coh_i(&deg[r]));
                    }
            }
            st_coh(&W[v], acc * invd);
        }

        // -- levels 1..8 (V3..V10): spin-gather previous level, publish --
        #pragma unroll 1
        for (int k = 1; k < NLVL; ++k) {
            const float* Wp = W + (size_t)(k - 1) * NP1;
            unsigned uv[CAP];
            unsigned pend = (unsigned)((1ull << cnt) - 1ull);
            int guard = 0;
            while (pend) {
                // batched issue of still-pending loads (MLP), then check
                #pragma unroll
                for (int s = 0; s < CAP; ++s)
                    if ((pend >> s) & 1u)
                        uv[s] = ld_coh_u((const unsigned*)&Wp[er[s]]);
                unsigned np = pend;
                #pragma unroll
                for (int s = 0; s < CAP; ++s)
                    if (((pend >> s) & 1u) && uv[s] != NANP) np &= ~(1u << s);
                pend = np;
                if (pend) {
                    if (++guard > SPIN_MAX) break;   // watchdog: NaN flows to
                    __builtin_amdgcn_s_sleep(2);     // output -> diagnosable
                }
            }
            float acc = dposv;
            #pragma unroll
            for (int s = 0; s < CAP; ++s)                 // deterministic order
                if (s < cnt) acc += __uint_as_float(uv[s]);
            if (ocnt > 0) {                               // exactness fallback
                for (int o = 0; o < ocnt && o < OFL_MAX; ++o)
                    if (ld_coh_i(&ofl_v[o]) == v) {
                        int r = ld_coh_i(&ofl_row[o]);
                        unsigned u = NANP;
                        for (int t = 0; t < SPIN_MAX; ++t) {
                            u = ld_coh_u((const unsigned*)&Wp[r]);
                            if (u != NANP) break;
                        }
                        acc += __uint_as_float(u);
                    }
            }
            st_coh(&W[(size_t)k * NP1 + v], acc * invd);
        }
    }
    gbar(grp, ++bar);

    // ---- out[e] = V_10[row_e]; float4 stores ----
    if (bld) {
        const float* W9 = W + (size_t)(NLVL - 1) * NP1;
        float4 o4;
        o4.x = ld_coh(&W9[r4.x]);
        o4.y = ld_coh(&W9[r4.y]);
        o4.z = ld_coh(&W9[r4.z]);
        o4.w = ld_coh(&W9[r4.w]);
        ((float4*)out)[m] = o4;
    }
}

extern "C" void kernel_launch(void* const* d_in, const int* in_sizes, int n_in,
                              void* d_out, int out_size, void* d_ws, size_t ws_size,
                              hipStream_t stream) {
    const float* demands  = (const float*)d_in[1];
    const int*   edge_row = (const int*)d_in[2];
    const int*   edge_col = (const int*)d_in[3];
    float*       out      = (float*)d_out;

    char* ws = (char*)d_ws;
    auto take = [&](size_t bytes) {
        void* p = (void*)ws;
        ws += (bytes + 127) & ~size_t(127);
        return p;
    };
    // ---- zero zone (0x00 memset) ----
    char* zone0 = ws;
    int*   deg     = (int*)  take(N_NODES * 4);
    int*   fill    = (int*)  take(N_NODES * 4);
    int*   ofl_cnt = (int*)  take(4);
    int*   grp     = (int*)  take(8 * 32 * 4);
    size_t zone0_bytes = (size_t)(ws - zone0);
    // ---- 0xFF zone (NaN-tag levels) ----
    char* zoneF = ws;
    float* W       = (float*)take((size_t)NLVL * NP1 * 4);
    size_t zoneF_bytes = (size_t)(ws - zoneF);
    // ---- uninitialized zone ----
    int*   pcsc    = (int*)  take((size_t)N_NODES * CAP * 4);
    int*   ofl_v   = (int*)  take(OFL_MAX * 4);
    int*   ofl_row = (int*)  take(OFL_MAX * 4);

    hipMemsetAsync(zone0, 0x00, zone0_bytes, stream);
    hipMemsetAsync(zoneF, 0xFF, zoneF_bytes, stream);
    mcf_fused<<<NBLK, NTHR, 0, stream>>>(demands, edge_row, edge_col, out,
                                         deg, fill, W, pcsc,
                                         ofl_cnt, ofl_v, ofl_row, grp);
}